// Round 10
// baseline (147.440 us; speedup 1.0000x reference)
//
#include <hip/hip_runtime.h>
#include <stdint.h>

// MemoryEfficientBSpline: out[b,o,p] = sum_i sum_g hat_g(nx[b,i,p]) * coef[b,o,i,g]
// hat_g(nx) = max(0, 1 - |nx - g|),  nx = clamp(x*2.5+2.5, 0, 5) in [0,5], G=6.
// Batched GEMM M=64(o) x N=36864(p) x K=384(i*G) via mfma_f32_16x16x32_f16.
//
// v11 = v10 resubmitted (round-9 bench died to "container failed twice" --
// infra, same as round 4; audit of index math / barriers / asm found no
// defect). Single-variable probe of the STORE PATH vs v6 (best, 60.6us):
//   old: 48 scalar global_store_dword/thread, 4x64B scattered segments/instr,
//        295K store instrs, writes stream through L3 evicting x (FETCH stuck
//        at 40MB = half of x re-fetched from HBM every dispatch).
//   new: acc transposed through LDS (overlaid on dead A_lds, exact 50176B fit,
//        196-word padded rows -> 2-way banks = free), then row-contiguous
//        nontemporal dwordx4 stores: 1KB per wave-instr in 2-3 full-line
//        segments (4x fewer instrs, 8x fewer segments), nt keeps x L3-resident.
// Readout: dur drop => store path was the hidden constant. FETCH drop => nt
// L3-preservation works. WRITE balloon >85MB => nt hurts, drop it next.

typedef __fp16 half8_t __attribute__((ext_vector_type(8)));
typedef __fp16 half2_t __attribute__((ext_vector_type(2)));
typedef float f32x4 __attribute__((ext_vector_type(4)));

#define NBATCH 8
#define OD 64
#define ID 64
#define PIX 36864          // 192*192
#define NG 6
#define PT 192             // pixels per block tile (4 waves x 48)
#define KI 16              // i per chunk
#define NCHUNK 4           // 4 * 16 = 64 = ID
#define KC (KI * NG)       // 96 k-values per chunk (g-major: k = g*16 + iof)
#define AROW 392           // coef f16 row stride: 384 used + 8 pad
#define SROW 196           // epilogue f32 row stride: 192 used + 4 pad (16B-aligned,
                           // q8-step 784 words % 32 = 16 -> 2-way banks, free)
#define PTILES (PIX / PT)  // 192 p-tiles per batch

// Issue 24 sink-proof loads for chunk cc into dst[24] (quarter-wave 64B coalesced).
// One asm stmt per j: 3 loads, early-clobber dests so none aliases the addr pair.
#define LOADCHUNK(dst, cc)                                                      \
  do {                                                                          \
    _Pragma("unroll") for (int j = 0; j < 8; ++j) {                             \
      const float* a_ = xb + (size_t)((cc) * KI + j) * PIX;                     \
      asm volatile("global_load_dword %0, %3, off\n\t"                          \
                   "global_load_dword %1, %3, off offset:64\n\t"                \
                   "global_load_dword %2, %3, off offset:128"                   \
                   : "=&v"(dst[j * 3 + 0]), "=&v"(dst[j * 3 + 1]),              \
                     "=&v"(dst[j * 3 + 2])                                      \
                   : "v"(a_));                                                  \
    }                                                                           \
    __builtin_amdgcn_sched_barrier(0);                                          \
  } while (0)

#define VMWAIT(n)                                                               \
  do {                                                                          \
    asm volatile("s_waitcnt vmcnt(" #n ")" ::: "memory");                       \
    __builtin_amdgcn_sched_barrier(0);                                          \
  } while (0)

__global__ __launch_bounds__(256, 3)
void kan_mfma(const float* __restrict__ x, const float* __restrict__ coef,
              float* __restrict__ out) {
  const int t = threadIdx.x;
  const int lane = t & 63;
  const int wave = t >> 6;      // 0..3, owns p sub-range [wave*48, wave*48+48)
  const int q8 = lane >> 4;     // 0..3
  const int col = lane & 15;

  const int bid = blockIdx.x;
  const int b = bid / PTILES;   // same-b blocks contiguous -> coef L2 locality
  const int ptile = bid % PTILES;
  const int p0 = ptile * PT;

  __shared__ __fp16 A_lds[OD][AROW] __attribute__((aligned(16)));  // 50176 B

  const int iof0 = (q8 & 1) * 8;  // which 8 i's this lane's fragment covers
  const int ghalf = q8 >> 1;      // g = 2*ks + ghalf
  const float* xb = x + (size_t)b * ID * PIX + p0 + wave * 48 + col
                      + (size_t)iof0 * PIX;

  float xA[24], xB[24];

  // ---- chunk 0's loads issue FIRST: latency hides under coef staging ----
  LOADCHUNK(xA, 0);

  // ---- stage ALL coef as f16, g-major per 16-i chunk: A[o][c*96 + g*16 + iof] ----
  {
    const int o = t >> 2;
    const int c = t & 3;
    const float* crow = coef + (size_t)b * (OD * ID * NG) + o * (ID * NG) + c * KC;
    __fp16* arow = &A_lds[o][c * KC];
#pragma unroll
    for (int blk = 0; blk < 8; ++blk) {  // 2 iof's per blk: src r = iof*6+g, r+6
      f32x4 va = ((const f32x4*)crow)[blk * 3 + 0];
      f32x4 vb = ((const f32x4*)crow)[blk * 3 + 1];
      f32x4 vc = ((const f32x4*)crow)[blk * 3 + 2];
      const float lo[NG] = {va[0], va[1], va[2], va[3], vb[0], vb[1]};
      const float hi[NG] = {vb[2], vb[3], vc[0], vc[1], vc[2], vc[3]};
#pragma unroll
      for (int g = 0; g < NG; ++g) {
        half2_t h2 = __builtin_amdgcn_cvt_pkrtz(lo[g], hi[g]);
        *(half2_t*)&arow[g * KI + blk * 2] = h2;  // 4B-aligned b32 write
      }
    }
  }

  f32x4 acc[4][3];
#pragma unroll
  for (int i = 0; i < 4; ++i)
#pragma unroll
    for (int j = 0; j < 3; ++j)
      acc[i][j] = (f32x4){0.f, 0.f, 0.f, 0.f};

  __syncthreads();  // barrier #1 (its drain covers chunk 0's loads)

#pragma unroll
  for (int c = 0; c < NCHUNK; ++c) {
    float* xc = (c & 1) ? xB : xA;  // static after full unroll
    float* xn = (c & 1) ? xA : xB;

    // ---- issue chunk c+1's 24 loads; they stay in flight through compute ----
    if (c + 1 < NCHUNK) {
      LOADCHUNK(xn, c + 1);
      VMWAIT(24);  // >=24 retired in-order => all of chunk c landed
    } else {
      VMWAIT(0);
    }

    // ---- nx for my 24 (p, i) pairs ----
    float nxv[3][8];
#pragma unroll
    for (int j = 0; j < 8; ++j) {
#pragma unroll
      for (int pt = 0; pt < 3; ++pt)
        nxv[pt][j] = fminf(fmaxf(xc[j * 3 + pt] * 2.5f + 2.5f, 0.f), 5.f);
    }

#pragma unroll
    for (int ks = 0; ks < 3; ++ks) {
      half8_t af[4];
#pragma unroll
      for (int ot = 0; ot < 4; ++ot)
        af[ot] = *(const half8_t*)&A_lds[ot * 16 + col][c * KC + ks * 32 + q8 * 8];

      const float gf = (float)(2 * ks + ghalf);
#pragma unroll
      for (int pti = 0; pti < 3; ++pti) {
        union { half2_t h2[4]; half8_t v; } bu;
#pragma unroll
        for (int jj = 0; jj < 4; ++jj) {
          float h0 = 1.f - fabsf(nxv[pti][2 * jj] - gf);
          float h1 = 1.f - fabsf(nxv[pti][2 * jj + 1] - gf);
          half2_t h2 = __builtin_amdgcn_cvt_pkrtz(h0, h1);
          bu.h2[jj] = __builtin_elementwise_max(h2, (half2_t)(__fp16)0.f);
        }
#pragma unroll
        for (int ot = 0; ot < 4; ++ot)
          acc[ot][pti] = __builtin_amdgcn_mfma_f32_16x16x32_f16(
              af[ot], bu.v, acc[ot][pti], 0, 0, 0);
      }
    }
  }

  // ==== epilogue: transpose through LDS, coalesced nontemporal stores ====
  __syncthreads();  // barrier #2: all waves done reading A_lds -> safe to overlay
  float* S = (float*)&A_lds[0][0];  // S[64][SROW=196] f32 = 50176 B, exact fit
#pragma unroll
  for (int ot = 0; ot < 4; ++ot) {
#pragma unroll
    for (int pti = 0; pti < 3; ++pti) {
      int p = wave * 48 + pti * 16 + col;
#pragma unroll
      for (int r = 0; r < 4; ++r) {
        int o = ot * 16 + q8 * 4 + r;
        S[o * SROW + p] = acc[ot][pti][r];  // 2-way banks (q8-step 784%32=16)
      }
    }
  }
  __syncthreads();  // barrier #3

  // wave w stores o-rows [16w,16w+16): 12 x 1KB flat-contiguous instructions,
  // each 2-3 full-line (>=256B) global segments. nt: don't pollute L3 (keep x).
  {
    float* ob = out + (size_t)b * OD * PIX + p0;
#pragma unroll
    for (int k = 0; k < 12; ++k) {
      int flat = wave * 12288 + k * 1024 + lane * 16;  // byte offset in 64x768 tile
      int row = flat / 768;                            // magic-mul, no div
      int colw = (flat - row * 768) >> 2;              // word col 0..191
      f32x4 v = *(const f32x4*)&S[row * SROW + colw];
      __builtin_nontemporal_store(v, (f32x4*)(ob + (size_t)row * PIX + colw));
    }
  }
}

extern "C" void kernel_launch(void* const* d_in, const int* in_sizes, int n_in,
                              void* d_out, int out_size, void* d_ws, size_t ws_size,
                              hipStream_t stream) {
  const float* x = (const float*)d_in[0];
  const float* coef = (const float*)d_in[1];
  float* out = (float*)d_out;
  dim3 grid(NBATCH * PTILES);
  dim3 block(256);
  hipLaunchKernelGGL(kan_mfma, grid, block, 0, stream, x, coef, out);
}